// Round 11
// baseline (14960.851 us; speedup 1.0000x reference)
//
#include <hip/hip_runtime.h>
#include <math.h>

typedef __attribute__((ext_vector_type(8))) __bf16          bf16x8;
typedef __attribute__((ext_vector_type(8))) unsigned short  ushort8;
typedef __attribute__((ext_vector_type(4))) float           f32x4;
typedef __attribute__((ext_vector_type(4))) unsigned int    u32x4;

constexpr int Bb = 128, Hh = 1024, Tt = 384, BH = Bb * Hh;
constexpr int NWG = 256, BLK = 256;   // 4 layers x 32 cg x 2 row-halves, 4 waves/WG

// Fragment-linear X/H slot: 512 KB = 16 kcg x 32 blocks x 1 KB.
// block BI = kcg*32 + rgq*8 + rb*4 + pl*2 + ks ; lane = kg*16 + row16 at lane*16.
constexpr size_t SLOT_B  = 524288;
constexpr size_t OFF_H   = 1024;
constexpr size_t OFF_W   = OFF_H + 8 * SLOT_B;
constexpr size_t WBLK_B  = 24576;                     // per (m,cg,kcg): 24 blocks x 1 KB (96 cols)
constexpr size_t OFF_X   = OFF_W + 2048ull * WBLK_B;  // 4 mats x 32 cg x 16 kcg
constexpr size_t WS_FULL = OFF_X + 384ull * SLOT_B;

__device__ __forceinline__ float b2f(unsigned short h) {
    unsigned u = ((unsigned)h) << 16;
    return __builtin_bit_cast(float, u);
}
__device__ __forceinline__ void split_bf16(float x, unsigned short& hi, unsigned short& lo) {
    unsigned u  = __builtin_bit_cast(unsigned, x);
    unsigned uh = u & 0xFFFF0000u;
    hi = (unsigned short)(uh >> 16);
    float rem = x - __builtin_bit_cast(float, uh);     // exact
    unsigned ur = __builtin_bit_cast(unsigned, rem);
    ur += 0x7FFFu + ((ur >> 16) & 1u);                 // RNE
    lo = (unsigned short)(ur >> 16);
}
__device__ __forceinline__ void split8(const float* src, ushort8& h8, ushort8& l8) {
    const float4* p4 = (const float4*)src;
    float4 a = p4[0], b = p4[1];
    float v[8] = {a.x, a.y, a.z, a.w, b.x, b.y, b.z, b.w};
    #pragma unroll
    for (int m = 0; m < 8; ++m) { unsigned short h, l; split_bf16(v[m], h, l); h8[m] = h; l8[m] = l; }
}
__device__ __forceinline__ void async16(const void* g, void* l) {
    __builtin_amdgcn_global_load_lds(
        (const __attribute__((address_space(1))) unsigned int*)g,
        (__attribute__((address_space(3))) unsigned int*)l, 16, 0, 0);
}

// ---------------- prologue kernels (fragment-linear emit) ----------------

// weights -> wbuf[(m*32+cg)*16+kcg]: 24 blocks of 1KB, block = ct*4 + pl*2 + ks,
// ct = jh*3+g covers jcol = cg*32 + jh*16 + jl ; lane = kg*16 + jl.
__global__ void wsplit_kernel(const float* __restrict__ W0i, const float* __restrict__ W0h,
                              const float* __restrict__ W1i, const float* __restrict__ W1h,
                              char* __restrict__ wbuf) {
    int t = blockIdx.x * 256 + threadIdx.x;
    if (t >= 2048 * 96 * 8) return;
    int g8 = t & 7;
    int r  = (t >> 3) % 96;                  // ct*16 + jl
    int rest = (t >> 3) / 96;                // (m*32+cg)*16 + kcg
    int kcg = rest & 15, cg = (rest >> 4) & 31, m = rest >> 9;
    const float* W = (m == 0) ? W0i : (m == 1) ? W0h : (m == 2) ? W1i : W1h;
    int ct = r >> 4, jl = r & 15;
    int jh = ct / 3, g = ct % 3;
    const float* src = W + (size_t)((g << 10) + cg * 32 + jh * 16 + jl) * 1024 + kcg * 64 + g8 * 8;
    ushort8 h8, l8; split8(src, h8, l8);
    int ks = (g8 >> 2) & 1, kg = g8 & 3, lane = kg * 16 + jl;
    char* blk = wbuf + (size_t)rest * WBLK_B;
    int off0 = (ct * 4 + ks) * 1024 + lane * 16;   // pl=0 ; pl=1 at +2048
    *(ushort8*)(blk + off0)        = h8;
    *(ushort8*)(blk + off0 + 2048) = l8;
}

__global__ void xsplit_kernel(const float* __restrict__ xin, char* __restrict__ xb) {
    int t = blockIdx.x * 256 + threadIdx.x;
    if (t >= 384 * 128 * 128) return;
    int g8 = t & 127, b = (t >> 7) & 127, tau = t >> 14;
    const float* src = xin + ((size_t)b * 384 + tau) * 1024 + g8 * 8;
    ushort8 h8, l8; split8(src, h8, l8);
    int kcg = g8 >> 3, gin = g8 & 7;
    int ks = (gin >> 2) & 1, kg = gin & 3;
    int lane = kg * 16 + (b & 15);
    int BI0 = kcg * 32 + (b >> 5) * 8 + ((b >> 4) & 1) * 4 + ks;
    char* dst = xb + (size_t)tau * SLOT_B + (size_t)BI0 * 1024 + lane * 16;
    *(ushort8*)dst          = h8;
    *(ushort8*)(dst + 2048) = l8;
}

__global__ void hinit_kernel(const float* __restrict__ h0, char* __restrict__ ws) {
    int t = blockIdx.x * 256 + threadIdx.x;
    if (t == 0) *(unsigned*)ws = 0;
    if (t >= 4 * 128 * 128) return;
    char* hs = ws + OFF_H;
    int g8 = t & 127, b = (t >> 7) & 127, si = t >> 14;   // si 0..3 -> slot 1,3,5,7
    ushort8 h8, l8;
    if (si < 2) {
        split8(h0 + (size_t)si * BH + (size_t)b * 1024 + g8 * 8, h8, l8);
    } else {
        #pragma unroll
        for (int m = 0; m < 8; ++m) { h8[m] = 0; l8[m] = 0; }
    }
    int kcg = g8 >> 3, gin = g8 & 7;
    int ks = (gin >> 2) & 1, kg = gin & 3;
    int lane = kg * 16 + (b & 15);
    int BI0 = kcg * 32 + (b >> 5) * 8 + ((b >> 4) & 1) * 4 + ks;
    char* dst = hs + (size_t)(si * 2 + 1) * SLOT_B + (size_t)BI0 * 1024 + lane * 16;
    *(ushort8*)dst          = h8;
    *(ushort8*)(dst + 2048) = l8;
}

// ---------------- main persistent kernel ----------------

__device__ __forceinline__ void grid_barrier(unsigned* cnt, unsigned target) {
    __syncthreads();   // drains vmcnt(0): sc1 h-stores at coherent point
    if (threadIdx.x == 0) {
        __hip_atomic_fetch_add(cnt, 1u, __ATOMIC_RELEASE, __HIP_MEMORY_SCOPE_AGENT);
        while (__hip_atomic_load(cnt, __ATOMIC_RELAXED, __HIP_MEMORY_SCOPE_AGENT) < target)
            __builtin_amdgcn_s_sleep(1);
    }
    __syncthreads();
}

#define WAITVM(N) asm volatile("s_waitcnt vmcnt(" #N ")" ::: "memory")

// one pipeline iteration: wait chunk CH landed -> barrier -> issue CH+3 -> compute CH
#define GITER(CH, SLOT, ACC, WN, DOISS)                                  \
    WAITVM(WN);                                                          \
    asm volatile("" ::: "memory");                                       \
    __builtin_amdgcn_s_barrier();                                        \
    __builtin_amdgcn_sched_barrier(0);                                   \
    if (DOISS) { issueA((CH) + 3, ar[((SLOT) + 3) & 3]);                 \
                 issueB((CH) + 3, ((SLOT) + 3) & 3); }                   \
    computeC(ar[SLOT], (SLOT), ACC);

template<bool XS>
__global__ __launch_bounds__(BLK, 1) void gru_persistent(
    const float* __restrict__ xin,
    const float* __restrict__ bih0, const float* __restrict__ bhh0,
    const float* __restrict__ bih1, const float* __restrict__ bhh1,
    unsigned* __restrict__ cnt, char* __restrict__ ws)
{
    __shared__ char Bs[4][24576];    // 96 KiB: B 4-deep, fragment-linear (96 cols)

    char*       hs = ws + OFF_H;
    const char* wb = ws + OFF_W;
    const char* xs = ws + OFF_X;

    // XCD-pairing decode: siblings (rq=0,1) of a (layer,cg) pair differ by 8 in bid
    // -> same XCD under round-robin bid%8 placement (perf heuristic only).
    const int bid = blockIdx.x;
    const int xcd = bid & 7, sl = bid >> 3;
    const int pair = xcd * 16 + (sl >> 1), rq = sl & 1;
    const int layer = pair >> 5, cg = pair & 31;
    const int tid = threadIdx.x, lane = tid & 63, wv = tid >> 6;   // 4 waves

    const float* bih = (layer & 1) ? bih1 : bih0;
    const float* bhh = (layer & 1) ? bhh1 : bhh0;
    const int jl = lane & 15;

    // two owned jcols per lane (jh = 0,1); rows: b = rq*64 + wv*16 + (lane>>4)*4 + q
    int   kcg_j[2], ks_j[2], kg_j[2], e_j[2];
    float b_ir[2], b_hr[2], b_iz[2], b_hz[2], b_in[2], b_hn[2];
    #pragma unroll
    for (int jh = 0; jh < 2; ++jh) {
        int j = cg * 32 + jh * 16 + jl;
        kcg_j[jh] = j >> 6; ks_j[jh] = (j >> 5) & 1; kg_j[jh] = (j >> 3) & 3; e_j[jh] = j & 7;
        b_ir[jh] = bih[j];           b_hr[jh] = bhh[j];
        b_iz[jh] = bih[Hh + j];      b_hz[jh] = bhh[Hh + j];
        b_in[jh] = bih[2 * Hh + j];  b_hn[jh] = bhh[2 * Hh + j];
    }
    const int rowBI = (rq * 2 + (wv >> 1)) * 8 + (wv & 1) * 4;   // wave's A block base (per kcg)

    auto hoff = [&](int jh, int pl, int q) -> size_t {
        return (size_t)(kcg_j[jh] * 32 + rowBI + pl * 2 + ks_j[jh]) * 1024
             + (size_t)(kg_j[jh] * 16 + (lane >> 4) * 4 + q) * 16 + e_j[jh] * 2;
    };

    float hreg[8];          // h_old: [jh][q]
    const bool fb0 = (!XS) && (layer == 0);

    unsigned target = NWG;
    for (int s = 0; s < Tt + 3; ++s, target += NWG) {
        const int tau = s - layer;
        if (tau >= 0 && tau < Tt) {
            const char* Axb = (layer == 0) ? (xs + (size_t)tau * SLOT_B)
                                           : (hs + (size_t)(((layer - 1) * 2) + (tau & 1)) * SLOT_B);
            const char* Ahb = hs + (size_t)((layer * 2) + ((tau - 1) & 1)) * SLOT_B;
            char*       Hd  = hs + (size_t)((layer * 2) + (tau & 1)) * SLOT_B;

            if (tau == 0) {
                if (layer < 2) {
                    #pragma unroll
                    for (int jh = 0; jh < 2; ++jh)
                        #pragma unroll
                        for (int q = 0; q < 4; ++q) {
                            unsigned short hi = __hip_atomic_load(
                                (const unsigned short*)(Ahb + hoff(jh, 0, q)),
                                __ATOMIC_RELAXED, __HIP_MEMORY_SCOPE_AGENT);
                            unsigned short lo = __hip_atomic_load(
                                (const unsigned short*)(Ahb + hoff(jh, 1, q)),
                                __ATOMIC_RELAXED, __HIP_MEMORY_SCOPE_AGENT);
                            hreg[jh * 4 + q] = b2f(hi) + b2f(lo);
                        }
                    asm volatile("s_waitcnt vmcnt(0)" ::: "memory");  // clean ledger
                } else {
                    #pragma unroll
                    for (int i = 0; i < 8; ++i) hreg[i] = 0.f;
                }
            }

            // ---- staging: chunk ch in [0,32): ch<16 = X-stream, else H-stream ----
            auto issueA = [&](int ch, u32x4* fr) {       // 4 asm loads -> VGPR frags (16 rows)
                const char* p = ((ch < 16) ? Axb : Ahb)
                              + ((size_t)(ch & 15) << 15) + ((size_t)rowBI << 10) + (lane << 4);
                if (!(ch < 16 && layer == 0)) {
                    asm volatile("global_load_dwordx4 %0, %1, off sc0 sc1"             : "=v"(fr[0]) : "v"(p));
                    asm volatile("global_load_dwordx4 %0, %1, off offset:1024 sc0 sc1" : "=v"(fr[1]) : "v"(p));
                    asm volatile("global_load_dwordx4 %0, %1, off offset:2048 sc0 sc1" : "=v"(fr[2]) : "v"(p));
                    asm volatile("global_load_dwordx4 %0, %1, off offset:3072 sc0 sc1" : "=v"(fr[3]) : "v"(p));
                } else {
                    asm volatile("global_load_dwordx4 %0, %1, off"             : "=v"(fr[0]) : "v"(p));
                    asm volatile("global_load_dwordx4 %0, %1, off offset:1024" : "=v"(fr[1]) : "v"(p));
                    asm volatile("global_load_dwordx4 %0, %1, off offset:2048" : "=v"(fr[2]) : "v"(p));
                    asm volatile("global_load_dwordx4 %0, %1, off offset:3072" : "=v"(fr[3]) : "v"(p));
                }
            };
            auto issueB = [&](int ch, int buf) {         // 6 DMA -> LDS (cached weights)
                const int m = (layer & 1) * 2 + (ch < 16 ? 0 : 1);
                const char* Wb = wb + (size_t)(((m * 32 + cg) << 4) + (ch & 15)) * WBLK_B;
                char* L = &Bs[buf][0];
                #pragma unroll
                for (int i = 0; i < 6; ++i) {
                    int seg = wv + i * 4;
                    async16(Wb + seg * 1024 + lane * 16, L + seg * 1024);
                }
            };
            auto fragX = [&](int ch, u32x4* fr) {        // fb0: on-the-fly layer-0 X frags
                const int kcg = ch & 15;
                #pragma unroll
                for (int ks = 0; ks < 2; ++ks) {
                    int row = rq * 64 + wv * 16 + (lane & 15);
                    int k0  = kcg * 64 + ks * 32 + (lane >> 4) * 8;
                    ushort8 h8, l8;
                    split8(xin + ((size_t)row * 384 + tau) * 1024 + k0, h8, l8);
                    fr[ks]     = __builtin_bit_cast(u32x4, h8);
                    fr[2 + ks] = __builtin_bit_cast(u32x4, l8);
                }
            };
            auto computeC = [&](u32x4* fr, int buf, f32x4 (&acc)[6]) {
                const char* B = &Bs[buf][0];
                __builtin_amdgcn_s_setprio(1);
                #pragma unroll
                for (int ks = 0; ks < 2; ++ks) {
                    bf16x8 Ah = __builtin_bit_cast(bf16x8, fr[ks]);
                    bf16x8 Al = __builtin_bit_cast(bf16x8, fr[2 + ks]);
                    #pragma unroll
                    for (int ct = 0; ct < 6; ++ct) {
                        bf16x8 Bh = __builtin_bit_cast(bf16x8, *(const ushort8*)(B + (ct*4 + ks)*1024 + lane*16));
                        bf16x8 Bl = __builtin_bit_cast(bf16x8, *(const ushort8*)(B + (ct*4 + ks)*1024 + 2048 + lane*16));
                        f32x4 c = acc[ct];
                        c = __builtin_amdgcn_mfma_f32_16x16x32_bf16(Ah, Bh, c, 0, 0, 0);
                        c = __builtin_amdgcn_mfma_f32_16x16x32_bf16(Al, Bh, c, 0, 0, 0);
                        c = __builtin_amdgcn_mfma_f32_16x16x32_bf16(Ah, Bl, c, 0, 0, 0);
                        acc[ct] = c;
                    }
                }
                __builtin_amdgcn_s_setprio(0);
            };

            f32x4 accX[6], accH[6];
            const f32x4 zv = {0.f, 0.f, 0.f, 0.f};
            #pragma unroll
            for (int ct = 0; ct < 6; ++ct) { accX[ct] = zv; accH[ct] = zv; }

            u32x4 ar[4][4];   // A-fragment ring, static slots only

            if (!fb0) {
                // prologue: chunks 0,1,2 in flight (30 loads/wave)
                issueA(0, ar[0]); issueB(0, 0);
                issueA(1, ar[1]); issueB(1, 1);
                issueA(2, ar[2]); issueB(2, 2);
                for (int c4 = 0; c4 < 16; c4 += 4) {        // X chunks 0..15
                    GITER(c4 + 0, 0, accX, 20, true);
                    GITER(c4 + 1, 1, accX, 20, true);
                    GITER(c4 + 2, 2, accX, 20, true);
                    GITER(c4 + 3, 3, accX, 20, true);
                }
                for (int c4 = 16; c4 < 28; c4 += 4) {       // H chunks 16..27
                    GITER(c4 + 0, 0, accH, 20, true);
                    GITER(c4 + 1, 1, accH, 20, true);
                    GITER(c4 + 2, 2, accH, 20, true);
                    GITER(c4 + 3, 3, accH, 20, true);
                }
                GITER(28, 0, accH, 20, true);               // issues 31
                GITER(29, 1, accH, 20, false);
                GITER(30, 2, accH, 10, false);
                GITER(31, 3, accH, 0,  false);
            } else {
                // fallback: simple double-barrier loop, vmcnt(0) per iter
                for (int ch = 0; ch < 32; ++ch) {
                    if (ch < 16) fragX(ch, ar[0]); else issueA(ch, ar[0]);
                    issueB(ch, 0);
                    asm volatile("s_waitcnt vmcnt(0)" ::: "memory");
                    asm volatile("" ::: "memory");
                    __builtin_amdgcn_s_barrier();
                    __builtin_amdgcn_sched_barrier(0);
                    if (ch < 16) computeC(ar[0], 0, accX); else computeC(ar[0], 0, accH);
                    asm volatile("" ::: "memory");
                    __builtin_amdgcn_s_barrier();
                    asm volatile("" ::: "memory");
                }
            }

            // ---- gates + state update; h as sc1 atomic bf16 pairs ----
            #pragma unroll
            for (int jh = 0; jh < 2; ++jh)
                #pragma unroll
                for (int q = 0; q < 4; ++q) {
                    float rp = accX[jh*3 + 0][q] + accH[jh*3 + 0][q] + b_ir[jh] + b_hr[jh];
                    float zp = accX[jh*3 + 1][q] + accH[jh*3 + 1][q] + b_iz[jh] + b_hz[jh];
                    float xn = accX[jh*3 + 2][q] + b_in[jh];
                    float hn = accH[jh*3 + 2][q] + b_hn[jh];
                    float r  = 1.0f / (1.0f + expf(-rp));
                    float z  = 1.0f / (1.0f + expf(-zp));
                    float n  = tanhf(xn + r * hn);
                    float h  = (1.0f - z) * n + z * hreg[jh * 4 + q];
                    hreg[jh * 4 + q] = h;
                    unsigned short hi, lo; split_bf16(h, hi, lo);
                    __hip_atomic_store((unsigned short*)(Hd + hoff(jh, 0, q)), hi,
                                       __ATOMIC_RELAXED, __HIP_MEMORY_SCOPE_AGENT);
                    __hip_atomic_store((unsigned short*)(Hd + hoff(jh, 1, q)), lo,
                                       __ATOMIC_RELAXED, __HIP_MEMORY_SCOPE_AGENT);
                }
        }
        grid_barrier(cnt, target);
    }
}

__global__ void pred_kernel(const char* __restrict__ hs,
                            const float* __restrict__ linW,
                            const float* __restrict__ linb,
                            float* __restrict__ out) {
    const int b = blockIdx.x, l = threadIdx.x;   // 64 threads
    const char* slot = hs + 7 * SLOT_B;
    const int rpart = (b >> 5) * 8 + ((b >> 4) & 1) * 4;
    float s = 0.f;
    for (int u = l; u < Hh; u += 64) {
        int BI0 = (u >> 6) * 32 + rpart + ((u >> 5) & 1);
        size_t o = (size_t)BI0 * 1024 + (size_t)(((u >> 3) & 3) * 16 + (b & 15)) * 16 + (u & 7) * 2;
        float hv = b2f(*(const unsigned short*)(slot + o))
                 + b2f(*(const unsigned short*)(slot + o + 2048));
        s += hv * linW[u];
    }
    #pragma unroll
    for (int off = 32; off > 0; off >>= 1) s += __shfl_down(s, off);
    if (l == 0) out[b] = s + linb[0];
}

extern "C" void kernel_launch(void* const* d_in, const int* in_sizes, int n_in,
                              void* d_out, int out_size, void* d_ws, size_t ws_size,
                              hipStream_t stream) {
    const float* rand_in = (const float*)d_in[1];
    const float* h0      = (const float*)d_in[2];
    const float* Wih0    = (const float*)d_in[7];
    const float* Whh0    = (const float*)d_in[8];
    const float* bih0    = (const float*)d_in[9];
    const float* bhh0    = (const float*)d_in[10];
    const float* Wih1    = (const float*)d_in[11];
    const float* Whh1    = (const float*)d_in[12];
    const float* bih1    = (const float*)d_in[13];
    const float* bhh1    = (const float*)d_in[14];
    const float* linW    = (const float*)d_in[15];
    const float* linb    = (const float*)d_in[16];
    float* out = (float*)d_out;

    char*     ws  = (char*)d_ws;
    unsigned* cnt = (unsigned*)d_ws;
    char*     hsl = ws + OFF_H;

    const bool xsl = (ws_size >= WS_FULL);

    wsplit_kernel<<<6144, 256, 0, stream>>>(Wih0, Whh0, Wih1, Whh1, ws + OFF_W);
    hinit_kernel<<<256, 256, 0, stream>>>(h0, ws);
    if (xsl) {
        xsplit_kernel<<<24576, 256, 0, stream>>>(rand_in, ws + OFF_X);
        gru_persistent<true><<<NWG, BLK, 0, stream>>>(rand_in, bih0, bhh0, bih1, bhh1, cnt, ws);
    } else {
        gru_persistent<false><<<NWG, BLK, 0, stream>>>(rand_in, bih0, bhh0, bih1, bhh1, cnt, ws);
    }
    pred_kernel<<<Bb, 64, 0, stream>>>(hsl, linW, linb, out);
}

// Round 12
// 14530.852 us; speedup vs baseline: 1.0296x; 1.0296x over previous
//
#include <hip/hip_runtime.h>
#include <math.h>

typedef __attribute__((ext_vector_type(8))) __bf16          bf16x8;
typedef __attribute__((ext_vector_type(8))) unsigned short  ushort8;
typedef __attribute__((ext_vector_type(4))) float           f32x4;
typedef __attribute__((ext_vector_type(4))) unsigned int    u32x4;

constexpr int Bb = 128, Hh = 1024, Tt = 384, BH = Bb * Hh;
constexpr int NWG = 256, BLK = 256;   // 4 layers x 64 jwg (16 jcols), 4 waves/WG

// Fragment-linear X/H slot: 512 KB = 16 kcg x 32 blocks x 1 KB.
// block BI = kcg*32 + rg*8 + rb*4 + pl*2 + ks ; lane = kg*16 + row16 at lane*16.
constexpr size_t SLOT_B  = 524288;
constexpr size_t OFF_H   = 1024;
constexpr size_t OFF_W   = OFF_H + 8 * SLOT_B;
constexpr size_t WBLK_B  = 12288;                     // per (m,jwg,kcg): 12 blocks x 1 KB
constexpr size_t OFF_X   = OFF_W + 4096ull * WBLK_B;  // 4 mats x 64 jwg x 16 kcg
constexpr size_t WS_FULL = OFF_X + 384ull * SLOT_B;
// rotation region: slot(layer, tau) at index layer*385 + (tau+1); tau=-1..383
constexpr size_t OFF_R   = WS_FULL;
constexpr size_t WS_ROT  = OFF_R + 4ull * 385 * SLOT_B;   // ~1.07 GB total

__device__ __forceinline__ float b2f(unsigned short h) {
    unsigned u = ((unsigned)h) << 16;
    return __builtin_bit_cast(float, u);
}
__device__ __forceinline__ void split_bf16(float x, unsigned short& hi, unsigned short& lo) {
    unsigned u  = __builtin_bit_cast(unsigned, x);
    unsigned uh = u & 0xFFFF0000u;
    hi = (unsigned short)(uh >> 16);
    float rem = x - __builtin_bit_cast(float, uh);     // exact
    unsigned ur = __builtin_bit_cast(unsigned, rem);
    ur += 0x7FFFu + ((ur >> 16) & 1u);                 // RNE
    lo = (unsigned short)(ur >> 16);
}
__device__ __forceinline__ void split8(const float* src, ushort8& h8, ushort8& l8) {
    const float4* p4 = (const float4*)src;
    float4 a = p4[0], b = p4[1];
    float v[8] = {a.x, a.y, a.z, a.w, b.x, b.y, b.z, b.w};
    #pragma unroll
    for (int m = 0; m < 8; ++m) { unsigned short h, l; split_bf16(v[m], h, l); h8[m] = h; l8[m] = l; }
}
__device__ __forceinline__ void async16(const void* g, void* l) {
    __builtin_amdgcn_global_load_lds(
        (const __attribute__((address_space(1))) unsigned int*)g,
        (__attribute__((address_space(3))) unsigned int*)l, 16, 0, 0);
}

// ---------------- prologue kernels (fragment-linear emit, r10 layouts) ----------------

__global__ void wsplit_kernel(const float* __restrict__ W0i, const float* __restrict__ W0h,
                              const float* __restrict__ W1i, const float* __restrict__ W1h,
                              char* __restrict__ wbuf) {
    int t = blockIdx.x * 256 + threadIdx.x;
    if (t >= 4 * 64 * 16 * 48 * 8) return;
    int g8 = t & 7;
    int r  = (t >> 3) % 48;                  // ct*16 + jl
    int rest = (t >> 3) / 48;                // ((m*64+jwg)*16+kcg)
    int kcg = rest & 15, jwg = (rest >> 4) & 63, m = rest >> 10;
    const float* W = (m == 0) ? W0i : (m == 1) ? W0h : (m == 2) ? W1i : W1h;
    int ct = r >> 4, jl = r & 15;
    const float* src = W + (size_t)((ct << 10) + jwg * 16 + jl) * 1024 + kcg * 64 + g8 * 8;
    ushort8 h8, l8; split8(src, h8, l8);
    int ks = (g8 >> 2) & 1, kg = g8 & 3, lane = kg * 16 + jl;
    char* blk = wbuf + (size_t)rest * WBLK_B;
    int off0 = (ct * 4 + ks) * 1024 + lane * 16;   // pl=0 ; pl=1 at +2048
    *(ushort8*)(blk + off0)        = h8;
    *(ushort8*)(blk + off0 + 2048) = l8;
}

__global__ void xsplit_kernel(const float* __restrict__ xin, char* __restrict__ xb) {
    int t = blockIdx.x * 256 + threadIdx.x;
    if (t >= 384 * 128 * 128) return;
    int g8 = t & 127, b = (t >> 7) & 127, tau = t >> 14;
    const float* src = xin + ((size_t)b * 384 + tau) * 1024 + g8 * 8;
    ushort8 h8, l8; split8(src, h8, l8);
    int kcg = g8 >> 3, gin = g8 & 7;
    int ks = (gin >> 2) & 1, kg = gin & 3;
    int lane = kg * 16 + (b & 15);
    int BI0 = kcg * 32 + (b >> 5) * 8 + ((b >> 4) & 1) * 4 + ks;
    char* dst = xb + (size_t)tau * SLOT_B + (size_t)BI0 * 1024 + lane * 16;
    *(ushort8*)dst          = h8;
    *(ushort8*)(dst + 2048) = l8;
}

// h0 -> parity slots 1,3 (+zeros 5,7) and, if rot, rotation slots (layer, tau=-1).
__global__ void hinit_kernel(const float* __restrict__ h0, char* __restrict__ ws, int rot) {
    int t = blockIdx.x * 256 + threadIdx.x;
    if (t == 0) *(unsigned*)ws = 0;
    if (t >= 4 * 128 * 128) return;
    char* hs = ws + OFF_H;
    int g8 = t & 127, b = (t >> 7) & 127, si = t >> 14;   // si = layer
    ushort8 h8, l8;
    if (si < 2) {
        split8(h0 + (size_t)si * BH + (size_t)b * 1024 + g8 * 8, h8, l8);
    } else {
        #pragma unroll
        for (int m = 0; m < 8; ++m) { h8[m] = 0; l8[m] = 0; }
    }
    int kcg = g8 >> 3, gin = g8 & 7;
    int ks = (gin >> 2) & 1, kg = gin & 3;
    int lane = kg * 16 + (b & 15);
    int BI0 = kcg * 32 + (b >> 5) * 8 + ((b >> 4) & 1) * 4 + ks;
    size_t foff = (size_t)BI0 * 1024 + lane * 16;
    char* dst = hs + (size_t)(si * 2 + 1) * SLOT_B + foff;
    *(ushort8*)dst          = h8;
    *(ushort8*)(dst + 2048) = l8;
    if (rot) {
        char* dr = ws + OFF_R + (size_t)(si * 385) * SLOT_B + foff;   // tau = -1
        *(ushort8*)dr          = h8;
        *(ushort8*)(dr + 2048) = l8;
    }
}

// ---------------- main persistent kernel ----------------

__device__ __forceinline__ void grid_barrier(unsigned* cnt, unsigned target) {
    __syncthreads();   // drains vmcnt(0): sc1 h-stores at coherent point
    if (threadIdx.x == 0) {
        __hip_atomic_fetch_add(cnt, 1u, __ATOMIC_RELEASE, __HIP_MEMORY_SCOPE_AGENT);
        while (__hip_atomic_load(cnt, __ATOMIC_RELAXED, __HIP_MEMORY_SCOPE_AGENT) < target)
            __builtin_amdgcn_s_sleep(1);
    }
    __syncthreads();
}

#define WAITVM(N) asm volatile("s_waitcnt vmcnt(" #N ")" ::: "memory")

// one pipeline iteration: wait chunk CH landed -> barrier -> issue CH+3 -> compute CH
#define GITER(CH, SLOT, ACC, WN, DOISS)                                  \
    WAITVM(WN);                                                          \
    asm volatile("" ::: "memory");                                       \
    __builtin_amdgcn_s_barrier();                                        \
    __builtin_amdgcn_sched_barrier(0);                                   \
    if (DOISS) { issueA((CH) + 3, ar[((SLOT) + 3) & 3]);                 \
                 issueB((CH) + 3, ((SLOT) + 3) & 3); }                   \
    computeC(ar[SLOT], (SLOT), ACC);

// MODE: 0 = no-ws fallback (on-the-fly layer0 X, parity+sc) ; 1 = r10 exact ; 2 = rotation+cached
template<int MODE>
__global__ __launch_bounds__(BLK, 2) void gru_persistent(
    const float* __restrict__ xin,
    const float* __restrict__ bih0, const float* __restrict__ bhh0,
    const float* __restrict__ bih1, const float* __restrict__ bhh1,
    unsigned* __restrict__ cnt, char* __restrict__ ws)
{
    __shared__ char Bs[4][12288];    // 48 KiB: B 4-deep, fragment-linear

    char*       hs = ws + OFF_H;
    const char* wb = ws + OFF_W;
    const char* xs = ws + OFF_X;
    char*       rt = ws + OFF_R;

    const int bid = blockIdx.x, layer = bid >> 6, jwg = bid & 63, jbase = jwg * 16;
    const int tid = threadIdx.x, lane = tid & 63, rg = tid >> 6;   // 4 waves = 4 row groups

    const float* bih = (layer & 1) ? bih1 : bih0;
    const float* bhh = (layer & 1) ? bhh1 : bhh0;
    const int jl = lane & 15;
    const int jcol = jbase + jl;
    const float b_ir = bih[jcol],          b_hr = bhh[jcol];
    const float b_iz = bih[Hh + jcol],     b_hz = bhh[Hh + jcol];
    const float b_in = bih[2 * Hh + jcol], b_hn = bhh[2 * Hh + jcol];

    const int kcg_j = jcol >> 6, ks_j = (jcol >> 5) & 1, kg_j = (jcol >> 3) & 3, e_j = jcol & 7;
    const int baseBI = kcg_j * 32 + rg * 8 + ks_j;
    auto hoff = [&](int rb, int pl, int q) -> size_t {
        return (size_t)(baseBI + rb * 4 + pl * 2) * 1024
             + (size_t)(kg_j * 16 + (lane >> 4) * 4 + q) * 16 + e_j * 2;
    };

    float hreg[8];          // h_old: [rb][q]
    const bool fb0 = (MODE == 0) && (layer == 0);

    unsigned target = NWG;
    for (int s = 0; s < Tt + 3; ++s, target += NWG) {
        const int tau = s - layer;
        if (tau >= 0 && tau < Tt) {
            const char *Axb, *Ahb; char* Hd;
            if (MODE == 2) {
                Axb = (layer == 0) ? (xs + (size_t)tau * SLOT_B)
                                   : (rt + (size_t)((layer - 1) * 385 + tau + 1) * SLOT_B);
                Ahb = rt + (size_t)(layer * 385 + tau) * SLOT_B;         // slot(layer, tau-1)
                Hd  = rt + (size_t)(layer * 385 + tau + 1) * SLOT_B;     // slot(layer, tau)
            } else {
                Axb = (layer == 0) ? (xs + (size_t)tau * SLOT_B)
                                   : (hs + (size_t)(((layer - 1) * 2) + (tau & 1)) * SLOT_B);
                Ahb = hs + (size_t)((layer * 2) + ((tau - 1) & 1)) * SLOT_B;
                Hd  = hs + (size_t)((layer * 2) + (tau & 1)) * SLOT_B;
            }

            if (tau == 0) {
                if (layer < 2) {
                    #pragma unroll
                    for (int rb = 0; rb < 2; ++rb)
                        #pragma unroll
                        for (int q = 0; q < 4; ++q) {
                            unsigned short hi, lo;
                            if (MODE == 2) {
                                hi = *(const unsigned short*)(Ahb + hoff(rb, 0, q));
                                lo = *(const unsigned short*)(Ahb + hoff(rb, 1, q));
                            } else {
                                hi = __hip_atomic_load((const unsigned short*)(Ahb + hoff(rb, 0, q)),
                                                       __ATOMIC_RELAXED, __HIP_MEMORY_SCOPE_AGENT);
                                lo = __hip_atomic_load((const unsigned short*)(Ahb + hoff(rb, 1, q)),
                                                       __ATOMIC_RELAXED, __HIP_MEMORY_SCOPE_AGENT);
                            }
                            hreg[rb * 4 + q] = b2f(hi) + b2f(lo);
                        }
                    asm volatile("s_waitcnt vmcnt(0)" ::: "memory");  // clean ledger
                } else {
                    #pragma unroll
                    for (int i = 0; i < 8; ++i) hreg[i] = 0.f;
                }
            }

            // ---- staging: chunk ch in [0,32): ch<16 = X-stream, else H-stream ----
            auto issueA = [&](int ch, u32x4* fr) {       // 8 asm loads -> VGPR frags
                const char* base = ((ch < 16) ? Axb : Ahb)
                                 + ((size_t)(ch & 15) << 15) + (rg << 13) + (lane << 4);
                const bool coh = (MODE != 2) && !(ch < 16 && layer == 0);
                #pragma unroll
                for (int rb = 0; rb < 2; ++rb) {
                    const char* p = base + (rb << 12);
                    if (coh) {
                        asm volatile("global_load_dwordx4 %0, %1, off sc0 sc1"             : "=v"(fr[rb*4+0]) : "v"(p));
                        asm volatile("global_load_dwordx4 %0, %1, off offset:1024 sc0 sc1" : "=v"(fr[rb*4+1]) : "v"(p));
                        asm volatile("global_load_dwordx4 %0, %1, off offset:2048 sc0 sc1" : "=v"(fr[rb*4+2]) : "v"(p));
                        asm volatile("global_load_dwordx4 %0, %1, off offset:3072 sc0 sc1" : "=v"(fr[rb*4+3]) : "v"(p));
                    } else {
                        asm volatile("global_load_dwordx4 %0, %1, off"             : "=v"(fr[rb*4+0]) : "v"(p));
                        asm volatile("global_load_dwordx4 %0, %1, off offset:1024" : "=v"(fr[rb*4+1]) : "v"(p));
                        asm volatile("global_load_dwordx4 %0, %1, off offset:2048" : "=v"(fr[rb*4+2]) : "v"(p));
                        asm volatile("global_load_dwordx4 %0, %1, off offset:3072" : "=v"(fr[rb*4+3]) : "v"(p));
                    }
                }
            };
            auto issueB = [&](int ch, int buf) {         // 3 DMA -> LDS (cached)
                const int m = (layer & 1) * 2 + (ch < 16 ? 0 : 1);
                const char* Wb = wb + (size_t)(((m * 64 + jwg) << 4) + (ch & 15)) * WBLK_B;
                char* L = &Bs[buf][0];
                #pragma unroll
                for (int i = 0; i < 3; ++i) {
                    int seg = rg + i * 4;
                    async16(Wb + seg * 1024 + lane * 16, L + seg * 1024);
                }
            };
            auto fragX = [&](int ch, u32x4* fr) {        // MODE0: on-the-fly layer-0 X frags
                const int kcg = ch & 15;
                #pragma unroll
                for (int rb = 0; rb < 2; ++rb)
                    #pragma unroll
                    for (int ks = 0; ks < 2; ++ks) {
                        int row = rg * 32 + rb * 16 + (lane & 15);
                        int k0  = kcg * 64 + ks * 32 + (lane >> 4) * 8;
                        ushort8 h8, l8;
                        split8(xin + ((size_t)row * 384 + tau) * 1024 + k0, h8, l8);
                        fr[rb * 4 + ks]     = __builtin_bit_cast(u32x4, h8);
                        fr[rb * 4 + 2 + ks] = __builtin_bit_cast(u32x4, l8);
                    }
            };
            auto computeC = [&](u32x4* fr, int buf, f32x4 (&acc)[2][3]) {
                const char* B = &Bs[buf][0];
                __builtin_amdgcn_s_setprio(1);
                #pragma unroll
                for (int ks = 0; ks < 2; ++ks) {
                    bf16x8 Bh[3], Bl[3];
                    #pragma unroll
                    for (int ct = 0; ct < 3; ++ct) {
                        Bh[ct] = __builtin_bit_cast(bf16x8, *(const ushort8*)(B + (ct*4 + ks)*1024 + lane*16));
                        Bl[ct] = __builtin_bit_cast(bf16x8, *(const ushort8*)(B + (ct*4 + 2 + ks)*1024 + lane*16));
                    }
                    #pragma unroll
                    for (int rb = 0; rb < 2; ++rb) {
                        bf16x8 Ah = __builtin_bit_cast(bf16x8, fr[rb*4 + ks]);
                        bf16x8 Al = __builtin_bit_cast(bf16x8, fr[rb*4 + 2 + ks]);
                        #pragma unroll
                        for (int ct = 0; ct < 3; ++ct) {
                            f32x4 c = acc[rb][ct];
                            c = __builtin_amdgcn_mfma_f32_16x16x32_bf16(Ah, Bh[ct], c, 0, 0, 0);
                            c = __builtin_amdgcn_mfma_f32_16x16x32_bf16(Al, Bh[ct], c, 0, 0, 0);
                            c = __builtin_amdgcn_mfma_f32_16x16x32_bf16(Ah, Bl[ct], c, 0, 0, 0);
                            acc[rb][ct] = c;
                        }
                    }
                }
                __builtin_amdgcn_s_setprio(0);
            };

            f32x4 accX[2][3], accH[2][3];
            const f32x4 zv = {0.f, 0.f, 0.f, 0.f};
            #pragma unroll
            for (int rb = 0; rb < 2; ++rb)
                #pragma unroll
                for (int ct = 0; ct < 3; ++ct) { accX[rb][ct] = zv; accH[rb][ct] = zv; }

            u32x4 ar[4][8];   // A-fragment ring, static slots only

            if (!fb0) {
                // prologue: chunks 0,1,2 in flight (33 loads/wave)
                issueA(0, ar[0]); issueB(0, 0);
                issueA(1, ar[1]); issueB(1, 1);
                issueA(2, ar[2]); issueB(2, 2);
                for (int c4 = 0; c4 < 16; c4 += 4) {        // X chunks 0..15
                    GITER(c4 + 0, 0, accX, 22, true);
                    GITER(c4 + 1, 1, accX, 22, true);
                    GITER(c4 + 2, 2, accX, 22, true);
                    GITER(c4 + 3, 3, accX, 22, true);
                }
                for (int c4 = 16; c4 < 28; c4 += 4) {       // H chunks 16..27
                    GITER(c4 + 0, 0, accH, 22, true);
                    GITER(c4 + 1, 1, accH, 22, true);
                    GITER(c4 + 2, 2, accH, 22, true);
                    GITER(c4 + 3, 3, accH, 22, true);
                }
                GITER(28, 0, accH, 22, true);               // issues 31
                GITER(29, 1, accH, 22, false);
                GITER(30, 2, accH, 11, false);
                GITER(31, 3, accH, 0,  false);
            } else {
                // fallback: simple double-barrier loop, vmcnt(0) per iter
                for (int ch = 0; ch < 32; ++ch) {
                    if (ch < 16) fragX(ch, ar[0]); else issueA(ch, ar[0]);
                    issueB(ch, 0);
                    asm volatile("s_waitcnt vmcnt(0)" ::: "memory");
                    asm volatile("" ::: "memory");
                    __builtin_amdgcn_s_barrier();
                    __builtin_amdgcn_sched_barrier(0);
                    if (ch < 16) computeC(ar[0], 0, accX); else computeC(ar[0], 0, accH);
                    asm volatile("" ::: "memory");
                    __builtin_amdgcn_s_barrier();
                    asm volatile("" ::: "memory");
                }
            }

            // ---- gates + state update; h as sc1 atomic bf16 pairs (coherent point push) ----
            #pragma unroll
            for (int rb = 0; rb < 2; ++rb)
                #pragma unroll
                for (int q = 0; q < 4; ++q) {
                    float rp = accX[rb][0][q] + accH[rb][0][q] + b_ir + b_hr;
                    float zp = accX[rb][1][q] + accH[rb][1][q] + b_iz + b_hz;
                    float xn = accX[rb][2][q] + b_in;
                    float hn = accH[rb][2][q] + b_hn;
                    float r  = 1.0f / (1.0f + expf(-rp));
                    float z  = 1.0f / (1.0f + expf(-zp));
                    float n  = tanhf(xn + r * hn);
                    float h  = (1.0f - z) * n + z * hreg[rb * 4 + q];
                    hreg[rb * 4 + q] = h;
                    unsigned short hi, lo; split_bf16(h, hi, lo);
                    __hip_atomic_store((unsigned short*)(Hd + hoff(rb, 0, q)), hi,
                                       __ATOMIC_RELAXED, __HIP_MEMORY_SCOPE_AGENT);
                    __hip_atomic_store((unsigned short*)(Hd + hoff(rb, 1, q)), lo,
                                       __ATOMIC_RELAXED, __HIP_MEMORY_SCOPE_AGENT);
                }
        }
        grid_barrier(cnt, target);
    }
}

__global__ void pred_kernel(const char* __restrict__ slot,
                            const float* __restrict__ linW,
                            const float* __restrict__ linb,
                            float* __restrict__ out) {
    const int b = blockIdx.x, l = threadIdx.x;   // 64 threads
    const int rpart = (b >> 5) * 8 + ((b >> 4) & 1) * 4;
    float s = 0.f;
    for (int u = l; u < Hh; u += 64) {
        int BI0 = (u >> 6) * 32 + rpart + ((u >> 5) & 1);
        size_t o = (size_t)BI0 * 1024 + (size_t)(((u >> 3) & 3) * 16 + (b & 15)) * 16 + (u & 7) * 2;
        float hv = b2f(*(const unsigned short*)(slot + o))
                 + b2f(*(const unsigned short*)(slot + o + 2048));
        s += hv * linW[u];
    }
    #pragma unroll
    for (int off = 32; off > 0; off >>= 1) s += __shfl_down(s, off);
    if (l == 0) out[b] = s + linb[0];
}

extern "C" void kernel_launch(void* const* d_in, const int* in_sizes, int n_in,
                              void* d_out, int out_size, void* d_ws, size_t ws_size,
                              hipStream_t stream) {
    const float* rand_in = (const float*)d_in[1];
    const float* h0      = (const float*)d_in[2];
    const float* Wih0    = (const float*)d_in[7];
    const float* Whh0    = (const float*)d_in[8];
    const float* bih0    = (const float*)d_in[9];
    const float* bhh0    = (const float*)d_in[10];
    const float* Wih1    = (const float*)d_in[11];
    const float* Whh1    = (const float*)d_in[12];
    const float* bih1    = (const float*)d_in[13];
    const float* bhh1    = (const float*)d_in[14];
    const float* linW    = (const float*)d_in[15];
    const float* linb    = (const float*)d_in[16];
    float* out = (float*)d_out;

    char*     ws  = (char*)d_ws;
    unsigned* cnt = (unsigned*)d_ws;

    const bool rot = (ws_size >= WS_ROT);
    const bool xsl = (ws_size >= WS_FULL);

    wsplit_kernel<<<6144, 256, 0, stream>>>(Wih0, Whh0, Wih1, Whh1, ws + OFF_W);
    hinit_kernel<<<256, 256, 0, stream>>>(h0, ws, rot ? 1 : 0);
    const char* pslot;
    if (rot) {
        xsplit_kernel<<<24576, 256, 0, stream>>>(rand_in, ws + OFF_X);
        gru_persistent<2><<<NWG, BLK, 0, stream>>>(rand_in, bih0, bhh0, bih1, bhh1, cnt, ws);
        pslot = ws + OFF_R + (size_t)(3 * 385 + 384) * SLOT_B;   // slot(layer3, tau=383)
    } else if (xsl) {
        xsplit_kernel<<<24576, 256, 0, stream>>>(rand_in, ws + OFF_X);
        gru_persistent<1><<<NWG, BLK, 0, stream>>>(rand_in, bih0, bhh0, bih1, bhh1, cnt, ws);
        pslot = ws + OFF_H + 7 * SLOT_B;
    } else {
        gru_persistent<0><<<NWG, BLK, 0, stream>>>(rand_in, bih0, bhh0, bih1, bhh1, cnt, ws);
        pslot = ws + OFF_H + 7 * SLOT_B;
    }
    pred_kernel<<<Bb, 64, 0, stream>>>(pslot, linW, linb, out);
}